// Round 3
// 123.299 us; speedup vs baseline: 1.0059x; 1.0059x over previous
//
#include <hip/hip_runtime.h>
#include <math.h>

// ---------------- problem constants ----------------
#define NBLOCKS 2048
#define THREADS 256               // 4 waves/block
#define TILE 64
#define POS_PER_BLOCK 512         // one j-row per block: i, b constant
#define ITERS 8
#define CH 512                    // ushorts per k'-chunk: 64 pos * 8

typedef __attribute__((ext_vector_type(8)))  short  short8;   // MFMA A/B frag
typedef __attribute__((ext_vector_type(4)))  float  float4v;
typedef __attribute__((ext_vector_type(16))) float  float16;  // 32x32 C/D frag

// gfx950 packed f32x2 -> bf16x2 (RNE), single VALU instruction
__device__ __forceinline__ unsigned cvt_pk(float lo, float hi) {
    unsigned r;
    asm("v_cvt_pk_bf16_f32 %0, %1, %2" : "=v"(r) : "v"(lo), "v"(hi));
    return r;
}

// NOTE (R1/R2 session evidence): replacing the fmaxf-pair relu with
// v_pk_max_i16-on-packed-bf16 produced NaN output in two independent runs
// (R2 was single-variable vs this exact baseline). Do NOT reintroduce it.
// Likely mechanism: v_max_f32(NaN,0)->0 launders transient NaNs; i16-max
// passes the NaN bf16 pattern (positive i16) through to the output.

// k'-chunk map: chunk c (0..15), elem jj (0..7) -> channel.
// chunk c = 4*tile + 2*m + lh holds ch_local = (jj&3) + 8*(jj>>2) + 4lh + 16m,
// which is exactly the 32x32 MFMA C-reg octet m of a lane -> b128 everywhere.
__device__ __forceinline__ int kmap(int c, int jj) {
    return 32 * (c >> 2) + 16 * ((c >> 1) & 1) + 4 * (c & 1) + ((jj >> 2) << 3) + (jj & 3);
}

// launch_bounds(256,3): reg demand ~200 (a2f 64 + w1f 8 + w3a 16 + z16 16 +
// acc 32 + c1r/p + temps); forcing 4 blocks/CU (128-reg cap) over-subscribes
// ~70 regs -> spills/NaNs (R1). 3 blocks/CU is the structural ceiling here.
__global__ __launch_bounds__(256, 3)
void crpb_mfma8(const float* __restrict__ gq,   // (512,3)
                const float* __restrict__ gkv,  // (4,512,3)
                const float* __restrict__ W1,   // (3,128)
                const float* __restrict__ b1,   // (128,)
                const float* __restrict__ W2,   // (128,128)
                const float* __restrict__ b2,   // (128,)
                const float* __restrict__ W3,   // (128,4)
                const float* __restrict__ b3,   // (4,)
                float* __restrict__ out)        // (16,512,512)
{
    __shared__ __align__(16) unsigned short ash[2][16 * CH];   // 2 x 16 KB h1 tile
    __shared__ __align__(16) float red[2][2 * 4 * 64];         // 2 x 2 KB partials [ct2][o][pos]
    __shared__ __align__(16) float b2s[128];

    const int tid  = threadIdx.x;
    const int lane = tid & 63;
    const int w    = __builtin_amdgcn_readfirstlane(tid >> 6);  // 0..3
    const int l31  = lane & 31;
    const int lh   = lane >> 5;

    if (tid < 128) b2s[tid] = b2[tid];

    // wave role: ch-half ct2 (64 chs = tiles 2ct2, 2ct2+1), pos-half ph
    const int ct2 = w & 1;
    const int ph  = w >> 1;
    const int pofs = ph * 32 + l31;     // this lane's position within tile

    // persistent zero C-operand (shared by layer-1 and layer-3 MFMAs)
    float16 z16;
    #pragma unroll
    for (int r = 0; r < 16; ++r) z16[r] = 0.0f;

    // ---- layer-1 A-frags, W1 hi/lo split + b1 folded into spare K-slots ----
    // lh0 slots: (w0h,w0l),(w0h,w1h),(w1l,w1h),(w2h,w2l)  <-> B: (f0h,f0h),(f0l,f1h),(f1h,f1l),(f2h,f2h)
    // lh1 slots: (w2h,b1h),(b1l,0),0,0                    <-> B: (f2l,1.0),(1.0,0),0,0
    short8 w1f[2];
    #pragma unroll
    for (int mt = 0; mt < 2; ++mt) {
        const int ch = (ct2 * 2 + mt) * 32 + l31;
        const float w0 = W1[ch], w1v = W1[128 + ch], w2v = W1[256 + ch], b1v = b1[ch];
        const float w0h = __uint_as_float(cvt_pk(w0, w0) << 16);
        const float w1h = __uint_as_float(cvt_pk(w1v, w1v) << 16);
        const float w2h = __uint_as_float(cvt_pk(w2v, w2v) << 16);
        const float b1h = __uint_as_float(cvt_pk(b1v, b1v) << 16);
        const float w0l = w0 - w0h, w1l = w1v - w1h, w2l = w2v - w2h, b1l = b1v - b1h;
        unsigned d[4];
        if (lh == 0) {
            d[0] = cvt_pk(w0h, w0l);
            d[1] = cvt_pk(w0h, w1h);
            d[2] = cvt_pk(w1l, w1h);
            d[3] = cvt_pk(w2h, w2l);
        } else {
            d[0] = cvt_pk(w2h, b1h);
            d[1] = cvt_pk(b1l, 0.0f);
            d[2] = 0; d[3] = 0;
        }
        __builtin_memcpy(&w1f[mt], d, 16);
    }

    // ---- W2^T A-frags for BOTH ch tiles of this half (64 VGPRs) ----
    short8 a2f[2][8];
    #pragma unroll
    for (int mt = 0; mt < 2; ++mt) {
        const int e = ct2 * 64 + mt * 32 + l31;
        #pragma unroll
        for (int ks = 0; ks < 8; ++ks) {
            const int c = 2 * ks + lh;
            unsigned t0[4];
            #pragma unroll
            for (int t = 0; t < 4; ++t) {
                const int d0 = kmap(c, 2 * t), d1 = d0 + 1;
                t0[t] = cvt_pk(W2[d0 * 128 + e], W2[d1 * 128 + e]);
            }
            __builtin_memcpy(&a2f[mt][ks], t0, 16);
        }
    }

    // ---- W3 A-frags: 4 frags cover this half's 64 chs (16 VGPRs) ----
    short8 w3a[2][2];
    #pragma unroll
    for (int mt = 0; mt < 2; ++mt) {
        #pragma unroll
        for (int m2 = 0; m2 < 2; ++m2) {
            unsigned tt[4];
            #pragma unroll
            for (int t = 0; t < 4; ++t) {
                const int chl = ((2 * t) & 3) + 8 * ((2 * t) >> 2) + 4 * lh + 16 * m2;
                const int ch0 = (ct2 * 2 + mt) * 32 + chl, ch1 = ch0 + 1;
                const float lo = (l31 < 4) ? W3[ch0 * 4 + l31] : 0.0f;
                const float hi = (l31 < 4) ? W3[ch1 * 4 + l31] : 0.0f;
                tt[t] = cvt_pk(lo, hi);
            }
            __builtin_memcpy(&w3a[mt][m2], tt, 16);
        }
    }
    const float b3r = b3[w];   // phase R: o = tid>>6 = w

    // block-constant: one j-row (b, i fixed)
    const int posblock = blockIdx.x * POS_PER_BLOCK;
    const int bb = posblock >> 18;
    const int i  = (posblock >> 9) & 511;
    const float q0 = gq[i * 3 + 0], q1 = gq[i * 3 + 1], q2 = gq[i * 3 + 2];
    const float* kvrow = gkv + (size_t)(bb << 9) * 3;

    // prefetch tile 0's kv
    const float* kp = kvrow + (size_t)pofs * 3;
    float kv0 = kp[0], kv1 = kp[1], kv2 = kp[2];

    // ======== phase A: features -> layer-1 MFMA x2 -> ash[buf] ========
    auto phaseA = [&](int x, int buf) {
        const float c0 = q0 - kv0, c1 = q1 - kv1, c2 = q2 - kv2;
        const float* kn = kvrow + (size_t)((((x + 1) & 7) << 6) + pofs) * 3;
        kv0 = kn[0]; kv1 = kn[1]; kv2 = kn[2];

        const float f0 = copysignf(__logf(1.0f + fabsf(c0)), c0);
        const float f1 = copysignf(__logf(1.0f + fabsf(c1)), c1);
        const float f2 = copysignf(__logf(1.0f + fabsf(c2)), c2);
        const unsigned u0 = cvt_pk(f0, f0), u2 = cvt_pk(f2, f2);
        const float f0h = __uint_as_float(u0 << 16);
        const float f1h = __uint_as_float(cvt_pk(f1, f1) << 16);
        const float f2h = __uint_as_float(u2 << 16);
        const float f0l = f0 - f0h, f1l = f1 - f1h, f2l = f2 - f2h;

        unsigned d[4];
        if (lh == 0) {
            d[0] = u0;                    // (f0h, f0h)
            d[1] = cvt_pk(f0l, f1);       // (f0l, f1h)
            d[2] = cvt_pk(f1, f1l);       // (f1h, f1l)
            d[3] = u2;                    // (f2h, f2h)
        } else {
            d[0] = cvt_pk(f2l, 1.0f);     // (f2l, 1.0)  <- 1.0 slots pick up b1
            d[1] = cvt_pk(1.0f, 0.0f);
            d[2] = 0; d[3] = 0;
        }
        short8 bf; __builtin_memcpy(&bf, d, 16);

        #pragma unroll
        for (int mt = 0; mt < 2; ++mt) {
            const int cti = ct2 * 2 + mt;
            float16 c1r = __builtin_amdgcn_mfma_f32_32x32x16_bf16(w1f[mt], bf, z16, 0, 0, 0);
            unsigned pk0[4], pk1[4];
            #pragma unroll
            for (int t = 0; t < 4; ++t) {
                pk0[t] = cvt_pk(fmaxf(c1r[2 * t], 0.f),     fmaxf(c1r[2 * t + 1], 0.f));
                pk1[t] = cvt_pk(fmaxf(c1r[8 + 2 * t], 0.f), fmaxf(c1r[8 + 2 * t + 1], 0.f));
            }
            short8 v0, v1;
            __builtin_memcpy(&v0, pk0, 16);
            __builtin_memcpy(&v1, pk1, 16);
            *(short8*)&ash[buf][(4 * cti + lh) * CH + pofs * 8]     = v0;   // m=0 octet
            *(short8*)&ash[buf][(4 * cti + 2 + lh) * CH + pofs * 8] = v1;   // m=1 octet
        }
    };

    phaseA(0, 0);
    __syncthreads();   // also fences b2s staging

    for (int it = 0; it < ITERS; ++it) {
        const int buf = it & 1;
        const int jb = it * TILE;

        // ======== phase B: layer-2; 8 B-reads feed 16 MFMAs (2 ch tiles) ========
        float16 acc0, acc1;
        #pragma unroll
        for (int qr = 0; qr < 4; ++qr) {
            float4v i0 = *(const float4v*)&b2s[(ct2 * 2 + 0) * 32 + 8 * qr + 4 * lh];
            float4v i1 = *(const float4v*)&b2s[(ct2 * 2 + 1) * 32 + 8 * qr + 4 * lh];
            #pragma unroll
            for (int t = 0; t < 4; ++t) { acc0[4 * qr + t] = i0[t]; acc1[4 * qr + t] = i1[t]; }
        }
        const unsigned short* br = &ash[buf][lh * CH + pofs * 8];

        // T5: boost issue priority through the dense MFMA region. Resident
        // waves on a SIMD belong to 3 unsynced blocks (different phases), so
        // arbitration has something to pick between: this wave's MFMA chain
        // vs other waves' phase-A VALU (logs/cvt_pk).
        __builtin_amdgcn_s_setprio(1);
        #pragma unroll
        for (int ks = 0; ks < 8; ++ks) {
            short8 bfrag = *(const short8*)(br + ks * 2 * CH);
            acc0 = __builtin_amdgcn_mfma_f32_32x32x16_bf16(a2f[0][ks], bfrag, acc0, 0, 0, 0);
            acc1 = __builtin_amdgcn_mfma_f32_32x32x16_bf16(a2f[1][ks], bfrag, acc1, 0, 0, 0);
        }

        // ======== phase C': in-register relu + layer-3 (4 MFMAs, partial over 64 chs) ========
        {
            unsigned pa0[4], pa1[4], pb0[4], pb1[4];
            #pragma unroll
            for (int t = 0; t < 4; ++t) {
                pa0[t] = cvt_pk(fmaxf(acc0[2 * t], 0.f),     fmaxf(acc0[2 * t + 1], 0.f));
                pa1[t] = cvt_pk(fmaxf(acc0[8 + 2 * t], 0.f), fmaxf(acc0[8 + 2 * t + 1], 0.f));
                pb0[t] = cvt_pk(fmaxf(acc1[2 * t], 0.f),     fmaxf(acc1[2 * t + 1], 0.f));
                pb1[t] = cvt_pk(fmaxf(acc1[8 + 2 * t], 0.f), fmaxf(acc1[8 + 2 * t + 1], 0.f));
            }
            short8 fa0, fa1, fb0, fb1;
            __builtin_memcpy(&fa0, pa0, 16); __builtin_memcpy(&fa1, pa1, 16);
            __builtin_memcpy(&fb0, pb0, 16); __builtin_memcpy(&fb1, pb1, 16);
            float16 p;
            p = __builtin_amdgcn_mfma_f32_32x32x16_bf16(w3a[0][0], fa0, z16, 0, 0, 0);
            p = __builtin_amdgcn_mfma_f32_32x32x16_bf16(w3a[0][1], fa1, p, 0, 0, 0);
            p = __builtin_amdgcn_mfma_f32_32x32x16_bf16(w3a[1][0], fb0, p, 0, 0, 0);
            p = __builtin_amdgcn_mfma_f32_32x32x16_bf16(w3a[1][1], fb1, p, 0, 0, 0);
            __builtin_amdgcn_s_setprio(0);
            if (lh == 0) {
                #pragma unroll
                for (int o = 0; o < 4; ++o)
                    red[buf][ct2 * 256 + o * 64 + pofs] = p[o];
            }
        }

        // ======== phase A for next tile (other ash buffer) ========
        if (it != ITERS - 1) phaseA(it + 1, 1 - buf);

        __syncthreads();   // single barrier/tile: fences ash[1-buf] and red[buf]

        // ======== phase R: sum 2 ct2-partials + b3, coalesced store ========
        {
            const int o = w, pos = lane;
            const float v = b3r + red[buf][o * 64 + pos] + red[buf][256 + o * 64 + pos];
            out[((size_t)((bb << 2) + o) << 18) + ((size_t)i << 9) + jb + pos] = v;
        }
    }
}

extern "C" void kernel_launch(void* const* d_in, const int* in_sizes, int n_in,
                              void* d_out, int out_size, void* d_ws, size_t ws_size,
                              hipStream_t stream) {
    const float* gq  = (const float*)d_in[0];
    const float* gkv = (const float*)d_in[1];
    const float* W1  = (const float*)d_in[2];
    const float* b1  = (const float*)d_in[3];
    const float* W2  = (const float*)d_in[4];
    const float* b2  = (const float*)d_in[5];
    const float* W3  = (const float*)d_in[6];
    const float* b3  = (const float*)d_in[7];
    float* out = (float*)d_out;

    crpb_mfma8<<<NBLOCKS, THREADS, 0, stream>>>(gq, gkv, W1, b1, W2, b2, W3, b3, out);
}

// Round 4
// 122.721 us; speedup vs baseline: 1.0106x; 1.0047x over previous
//
#include <hip/hip_runtime.h>
#include <math.h>

// ---------------- problem constants ----------------
#define NBLOCKS 2048
#define THREADS 256               // 4 waves/block
#define TILE 64
#define POS_PER_BLOCK 512         // one j-row per block: i, b constant
#define ITERS 8
#define CH 512                    // ushorts per k'-chunk: 64 pos * 8

typedef __attribute__((ext_vector_type(8)))  short  short8;   // MFMA A/B frag
typedef __attribute__((ext_vector_type(4)))  float  float4v;
typedef __attribute__((ext_vector_type(4)))  unsigned uint4v;
typedef __attribute__((ext_vector_type(16))) float  float16;  // 32x32 C/D frag

// gfx950 packed f32x2 -> bf16x2 (RNE), single VALU instruction
__device__ __forceinline__ unsigned cvt_pk(float lo, float hi) {
    unsigned r;
    asm("v_cvt_pk_bf16_f32 %0, %1, %2" : "=v"(r) : "v"(lo), "v"(hi));
    return r;
}

// NOTE (R1/R2 session evidence): replacing the fmaxf-pair relu with
// v_pk_max_i16-on-packed-bf16 produced NaN output in two independent runs
// (R2 was single-variable vs the fmax baseline). Do NOT reintroduce it.
// Likely mechanism: v_max_f32(NaN,0)->0 launders transient NaNs; i16-max
// passes the NaN bf16 pattern (positive i16) through to the output.

// k'-chunk map: chunk c (0..15), elem jj (0..7) -> channel.
// chunk c = 4*tile + 2*m + lh holds ch_local = (jj&3) + 8*(jj>>2) + 4lh + 16m,
// which is exactly the 32x32 MFMA C-reg octet m of a lane -> b128 everywhere.
__device__ __forceinline__ int kmap(int c, int jj) {
    return 32 * (c >> 2) + 16 * ((c >> 1) & 1) + 4 * (c & 1) + ((jj >> 2) << 3) + (jj & 3);
}

// launch_bounds(256,3): reg demand ~200 (a2f 64 + w1f 8 + w3a 16 + z16 16 +
// acc 32 + c1r/p + temps); forcing 4 blocks/CU (128-reg cap) over-subscribes
// ~70 regs -> spills/NaNs (R1). 3 blocks/CU is the structural ceiling here.
__global__ __launch_bounds__(256, 3)
void crpb_mfma8(const float* __restrict__ gq,   // (512,3)
                const float* __restrict__ gkv,  // (4,512,3)
                const float* __restrict__ W1,   // (3,128)
                const float* __restrict__ b1,   // (128,)
                const float* __restrict__ W2,   // (128,128)
                const float* __restrict__ b2,   // (128,)
                const float* __restrict__ W3,   // (128,4)
                const float* __restrict__ b3,   // (4,)
                float* __restrict__ out)        // (16,512,512)
{
    __shared__ __align__(16) unsigned short ash[2][16 * CH];   // 2 x 16 KB h1 tile
    __shared__ __align__(16) float red[2][2 * 4 * 64];         // 2 x 2 KB partials [ct2][o][pos]
    __shared__ __align__(16) float b2s[128];
    // R4: per-block feature table (one j-row). fA = lh0 B-frag words (b128),
    // fB = lh1 word0 (word1 is the constant (1.0bf,0)). 10 KB; 47.6 KB total
    // LDS -> still 3 blocks/CU. Kills per-tile transcendental chains.
    __shared__ __align__(16) unsigned fA[512][4];
    __shared__ __align__(16) unsigned fB[512];

    const int tid  = threadIdx.x;
    const int lane = tid & 63;
    const int w    = __builtin_amdgcn_readfirstlane(tid >> 6);  // 0..3
    const int l31  = lane & 31;
    const int lh   = lane >> 5;

    if (tid < 128) b2s[tid] = b2[tid];

    // wave role: ch-half ct2 (64 chs = tiles 2ct2, 2ct2+1), pos-half ph
    const int ct2 = w & 1;
    const int ph  = w >> 1;
    const int pofs = ph * 32 + l31;     // this lane's position within tile

    // persistent zero C-operand (shared by layer-1 and layer-3 MFMAs)
    float16 z16;
    #pragma unroll
    for (int r = 0; r < 16; ++r) z16[r] = 0.0f;

    // ---- layer-1 A-frags, W1 hi/lo split + b1 folded into spare K-slots ----
    // lh0 slots: (w0h,w0l),(w0h,w1h),(w1l,w1h),(w2h,w2l)  <-> B: (f0h,f0h),(f0l,f1h),(f1h,f1l),(f2h,f2h)
    // lh1 slots: (w2h,b1h),(b1l,0),0,0                    <-> B: (f2l,1.0),(1.0,0),0,0
    short8 w1f[2];
    #pragma unroll
    for (int mt = 0; mt < 2; ++mt) {
        const int ch = (ct2 * 2 + mt) * 32 + l31;
        const float w0 = W1[ch], w1v = W1[128 + ch], w2v = W1[256 + ch], b1v = b1[ch];
        const float w0h = __uint_as_float(cvt_pk(w0, w0) << 16);
        const float w1h = __uint_as_float(cvt_pk(w1v, w1v) << 16);
        const float w2h = __uint_as_float(cvt_pk(w2v, w2v) << 16);
        const float b1h = __uint_as_float(cvt_pk(b1v, b1v) << 16);
        const float w0l = w0 - w0h, w1l = w1v - w1h, w2l = w2v - w2h, b1l = b1v - b1h;
        unsigned d[4];
        if (lh == 0) {
            d[0] = cvt_pk(w0h, w0l);
            d[1] = cvt_pk(w0h, w1h);
            d[2] = cvt_pk(w1l, w1h);
            d[3] = cvt_pk(w2h, w2l);
        } else {
            d[0] = cvt_pk(w2h, b1h);
            d[1] = cvt_pk(b1l, 0.0f);
            d[2] = 0; d[3] = 0;
        }
        __builtin_memcpy(&w1f[mt], d, 16);
    }

    // ---- W2^T A-frags for BOTH ch tiles of this half (64 VGPRs) ----
    short8 a2f[2][8];
    #pragma unroll
    for (int mt = 0; mt < 2; ++mt) {
        const int e = ct2 * 64 + mt * 32 + l31;
        #pragma unroll
        for (int ks = 0; ks < 8; ++ks) {
            const int c = 2 * ks + lh;
            unsigned t0[4];
            #pragma unroll
            for (int t = 0; t < 4; ++t) {
                const int d0 = kmap(c, 2 * t), d1 = d0 + 1;
                t0[t] = cvt_pk(W2[d0 * 128 + e], W2[d1 * 128 + e]);
            }
            __builtin_memcpy(&a2f[mt][ks], t0, 16);
        }
    }

    // ---- W3 A-frags: 4 frags cover this half's 64 chs (16 VGPRs) ----
    short8 w3a[2][2];
    #pragma unroll
    for (int mt = 0; mt < 2; ++mt) {
        #pragma unroll
        for (int m2 = 0; m2 < 2; ++m2) {
            unsigned tt[4];
            #pragma unroll
            for (int t = 0; t < 4; ++t) {
                const int chl = ((2 * t) & 3) + 8 * ((2 * t) >> 2) + 4 * lh + 16 * m2;
                const int ch0 = (ct2 * 2 + mt) * 32 + chl, ch1 = ch0 + 1;
                const float lo = (l31 < 4) ? W3[ch0 * 4 + l31] : 0.0f;
                const float hi = (l31 < 4) ? W3[ch1 * 4 + l31] : 0.0f;
                tt[t] = cvt_pk(lo, hi);
            }
            __builtin_memcpy(&w3a[mt][m2], tt, 16);
        }
    }
    const float b3r = b3[w];   // phase R: o = tid>>6 = w

    // block-constant: one j-row (b, i fixed)
    const int posblock = blockIdx.x * POS_PER_BLOCK;
    const int bb = posblock >> 18;
    const int i  = (posblock >> 9) & 511;
    const float q0 = gq[i * 3 + 0], q1 = gq[i * 3 + 1], q2 = gq[i * 3 + 2];
    const float* kvrow = gkv + (size_t)(bb << 9) * 3;

    // ---- feature precompute: whole j-row, once per block (2 pos/thread) ----
    // Bit-identical to the old per-tile computation (same ops, same rounding).
    for (int jj = tid; jj < 512; jj += THREADS) {
        const float k0 = kvrow[jj * 3 + 0], k1 = kvrow[jj * 3 + 1], k2 = kvrow[jj * 3 + 2];
        const float c0 = q0 - k0, c1 = q1 - k1, c2 = q2 - k2;
        const float f0 = copysignf(__logf(1.0f + fabsf(c0)), c0);
        const float f1 = copysignf(__logf(1.0f + fabsf(c1)), c1);
        const float f2 = copysignf(__logf(1.0f + fabsf(c2)), c2);
        const unsigned u0 = cvt_pk(f0, f0), u2 = cvt_pk(f2, f2);
        const float f0h = __uint_as_float(u0 << 16);
        const float f1h = __uint_as_float(cvt_pk(f1, f1) << 16);
        const float f2h = __uint_as_float(u2 << 16);
        const float f0l = f0 - f0h, f1l = f1 - f1h, f2l = f2 - f2h;
        fA[jj][0] = u0;                    // (f0h, f0h)
        fA[jj][1] = cvt_pk(f0l, f1);       // (f0l, f1h)
        fA[jj][2] = cvt_pk(f1, f1l);       // (f1h, f1l)
        fA[jj][3] = u2;                    // (f2h, f2h)
        fB[jj]    = cvt_pk(f2l, 1.0f);     // (f2l, 1.0) ; word1 is const
    }
    __syncthreads();   // features + b2s visible to all waves

    // ======== phase A: B-frag from LDS -> layer-1 MFMA x2 -> ash[buf] ========
    auto phaseA = [&](int x, int buf) {
        const int jpos = x * TILE + pofs;
        unsigned d[4];
        if (lh == 0) {
            const uint4v t = *(const uint4v*)&fA[jpos][0];
            d[0] = t[0]; d[1] = t[1]; d[2] = t[2]; d[3] = t[3];
        } else {
            d[0] = fB[jpos];
            d[1] = 0x00003F80u;            // (bf16 1.0, 0) <- picks up b1
            d[2] = 0; d[3] = 0;
        }
        short8 bf; __builtin_memcpy(&bf, d, 16);

        #pragma unroll
        for (int mt = 0; mt < 2; ++mt) {
            const int cti = ct2 * 2 + mt;
            float16 c1r = __builtin_amdgcn_mfma_f32_32x32x16_bf16(w1f[mt], bf, z16, 0, 0, 0);
            unsigned pk0[4], pk1[4];
            #pragma unroll
            for (int t = 0; t < 4; ++t) {
                pk0[t] = cvt_pk(fmaxf(c1r[2 * t], 0.f),     fmaxf(c1r[2 * t + 1], 0.f));
                pk1[t] = cvt_pk(fmaxf(c1r[8 + 2 * t], 0.f), fmaxf(c1r[8 + 2 * t + 1], 0.f));
            }
            short8 v0, v1;
            __builtin_memcpy(&v0, pk0, 16);
            __builtin_memcpy(&v1, pk1, 16);
            *(short8*)&ash[buf][(4 * cti + lh) * CH + pofs * 8]     = v0;   // m=0 octet
            *(short8*)&ash[buf][(4 * cti + 2 + lh) * CH + pofs * 8] = v1;   // m=1 octet
        }
    };

    phaseA(0, 0);
    __syncthreads();   // fences ash[0]

    for (int it = 0; it < ITERS; ++it) {
        const int buf = it & 1;
        const int jb = it * TILE;

        // ======== phase B: layer-2; 8 B-reads feed 16 MFMAs (2 ch tiles) ========
        float16 acc0, acc1;
        #pragma unroll
        for (int qr = 0; qr < 4; ++qr) {
            float4v i0 = *(const float4v*)&b2s[(ct2 * 2 + 0) * 32 + 8 * qr + 4 * lh];
            float4v i1 = *(const float4v*)&b2s[(ct2 * 2 + 1) * 32 + 8 * qr + 4 * lh];
            #pragma unroll
            for (int t = 0; t < 4; ++t) { acc0[4 * qr + t] = i0[t]; acc1[4 * qr + t] = i1[t]; }
        }
        const unsigned short* br = &ash[buf][lh * CH + pofs * 8];

        // T5: boost issue priority through the dense MFMA region (R3: -2.7%).
        __builtin_amdgcn_s_setprio(1);
        #pragma unroll
        for (int ks = 0; ks < 8; ++ks) {
            short8 bfrag = *(const short8*)(br + ks * 2 * CH);
            acc0 = __builtin_amdgcn_mfma_f32_32x32x16_bf16(a2f[0][ks], bfrag, acc0, 0, 0, 0);
            acc1 = __builtin_amdgcn_mfma_f32_32x32x16_bf16(a2f[1][ks], bfrag, acc1, 0, 0, 0);
        }

        // ======== phase C': in-register relu + layer-3 (4 MFMAs, partial over 64 chs) ========
        {
            unsigned pa0[4], pa1[4], pb0[4], pb1[4];
            #pragma unroll
            for (int t = 0; t < 4; ++t) {
                pa0[t] = cvt_pk(fmaxf(acc0[2 * t], 0.f),     fmaxf(acc0[2 * t + 1], 0.f));
                pa1[t] = cvt_pk(fmaxf(acc0[8 + 2 * t], 0.f), fmaxf(acc0[8 + 2 * t + 1], 0.f));
                pb0[t] = cvt_pk(fmaxf(acc1[2 * t], 0.f),     fmaxf(acc1[2 * t + 1], 0.f));
                pb1[t] = cvt_pk(fmaxf(acc1[8 + 2 * t], 0.f), fmaxf(acc1[8 + 2 * t + 1], 0.f));
            }
            short8 fa0, fa1, fb0, fb1;
            __builtin_memcpy(&fa0, pa0, 16); __builtin_memcpy(&fa1, pa1, 16);
            __builtin_memcpy(&fb0, pb0, 16); __builtin_memcpy(&fb1, pb1, 16);
            float16 p;
            p = __builtin_amdgcn_mfma_f32_32x32x16_bf16(w3a[0][0], fa0, z16, 0, 0, 0);
            p = __builtin_amdgcn_mfma_f32_32x32x16_bf16(w3a[0][1], fa1, p, 0, 0, 0);
            p = __builtin_amdgcn_mfma_f32_32x32x16_bf16(w3a[1][0], fb0, p, 0, 0, 0);
            p = __builtin_amdgcn_mfma_f32_32x32x16_bf16(w3a[1][1], fb1, p, 0, 0, 0);
            __builtin_amdgcn_s_setprio(0);
            if (lh == 0) {
                #pragma unroll
                for (int o = 0; o < 4; ++o)
                    red[buf][ct2 * 256 + o * 64 + pofs] = p[o];
            }
        }

        // ======== phase A for next tile (other ash buffer) ========
        if (it != ITERS - 1) phaseA(it + 1, 1 - buf);

        __syncthreads();   // single barrier/tile: fences ash[1-buf] and red[buf]

        // ======== phase R: sum 2 ct2-partials + b3, coalesced store ========
        {
            const int o = w, pos = lane;
            const float v = b3r + red[buf][o * 64 + pos] + red[buf][256 + o * 64 + pos];
            out[((size_t)((bb << 2) + o) << 18) + ((size_t)i << 9) + jb + pos] = v;
        }
    }
}

extern "C" void kernel_launch(void* const* d_in, const int* in_sizes, int n_in,
                              void* d_out, int out_size, void* d_ws, size_t ws_size,
                              hipStream_t stream) {
    const float* gq  = (const float*)d_in[0];
    const float* gkv = (const float*)d_in[1];
    const float* W1  = (const float*)d_in[2];
    const float* b1  = (const float*)d_in[3];
    const float* W2  = (const float*)d_in[4];
    const float* b2  = (const float*)d_in[5];
    const float* W3  = (const float*)d_in[6];
    const float* b3  = (const float*)d_in[7];
    float* out = (float*)d_out;

    crpb_mfma8<<<NBLOCKS, THREADS, 0, stream>>>(gq, gkv, W1, b1, W2, b2, W3, b3, out);
}

// Round 5
// 118.855 us; speedup vs baseline: 1.0435x; 1.0325x over previous
//
#include <hip/hip_runtime.h>
#include <math.h>

// ---------------- problem constants ----------------
#define NBLOCKS 2048
#define THREADS 512               // 8 waves/block (R5: halve per-wave state, double TLP)
#define TILE 64
#define POS_PER_BLOCK 512         // one j-row per block: i, b constant
#define ITERS 8
#define CH 512                    // ushorts per k'-chunk: 64 pos * 8

typedef __attribute__((ext_vector_type(8)))  short  short8;   // MFMA A/B frag
typedef __attribute__((ext_vector_type(4)))  float  float4v;
typedef __attribute__((ext_vector_type(4)))  unsigned uint4v;
typedef __attribute__((ext_vector_type(16))) float  float16;  // 32x32 C/D frag

// gfx950 packed f32x2 -> bf16x2 (RNE), single VALU instruction
__device__ __forceinline__ unsigned cvt_pk(float lo, float hi) {
    unsigned r;
    asm("v_cvt_pk_bf16_f32 %0, %1, %2" : "=v"(r) : "v"(lo), "v"(hi));
    return r;
}

// NOTE (R1/R2 session evidence): replacing the fmaxf-pair relu with
// v_pk_max_i16-on-packed-bf16 produced NaN output in two independent runs
// (R2 was single-variable vs the fmax baseline). Do NOT reintroduce it.
// R2 also exonerates launch-bound register caps as the NaN source: caps
// produce spills (slow but correct), relu_pk was the poison.

// k'-chunk map: chunk c (0..15), elem jj (0..7) -> channel.
// chunk c = 4*tile + 2*m + lh holds ch_local = (jj&3) + 8*(jj>>2) + 4lh + 16m,
// which is exactly the 32x32 MFMA C-reg octet m of a lane -> b128 everywhere.
__device__ __forceinline__ int kmap(int c, int jj) {
    return 32 * (c >> 2) + 16 * ((c >> 1) & 1) + 4 * (c & 1) + ((jj >> 2) << 3) + (jj & 3);
}

// R5 geometry: 8 waves, wave = (ct 0..3, ph 0..1); each wave owns ONE 32-ch
// tile (was two) -> per-wave regs ~110 (a2f 32 + acc 16 + z16 16 + w1f 4 +
// w3a 8 + temps). launch_bounds(512,4): 128-reg cap -> 2 blocks/CU
// = 16 waves/CU (~50% occ, was 26%). R4 proved the kernel is stall-bound,
// not issue-bound (removing 400 VALU/wave-iter changed nothing) -> TLP is
// the remaining lever.
__global__ __launch_bounds__(512, 4)
void crpb_mfma8(const float* __restrict__ gq,   // (512,3)
                const float* __restrict__ gkv,  // (4,512,3)
                const float* __restrict__ W1,   // (3,128)
                const float* __restrict__ b1,   // (128,)
                const float* __restrict__ W2,   // (128,128)
                const float* __restrict__ b2,   // (128,)
                const float* __restrict__ W3,   // (128,4)
                const float* __restrict__ b3,   // (4,)
                float* __restrict__ out)        // (16,512,512)
{
    __shared__ __align__(16) unsigned short ash[2][16 * CH];   // 2 x 16 KB h1 tile
    __shared__ __align__(16) float red[2][4 * 4 * 64];         // 2 x 4 KB partials [ct][o][pos]
    __shared__ __align__(16) float b2s[128];
    // per-block feature table (one j-row), B-frag word layout (R4).
    __shared__ __align__(16) unsigned fA[512][4];              // 8 KB
    __shared__ __align__(16) unsigned fB[512];                 // 2 KB

    const int tid  = threadIdx.x;
    const int lane = tid & 63;
    const int w    = __builtin_amdgcn_readfirstlane(tid >> 6);  // 0..7
    const int l31  = lane & 31;
    const int lh   = lane >> 5;

    if (tid < 128) b2s[tid] = b2[tid];

    // wave role: ch-tile ct (32 chs), pos-half ph
    const int ct = w & 3;
    const int ph = w >> 2;
    const int pofs = ph * 32 + l31;     // this lane's position within tile

    // persistent zero C-operand (shared by layer-1 and layer-3 MFMAs)
    float16 z16;
    #pragma unroll
    for (int r = 0; r < 16; ++r) z16[r] = 0.0f;

    // ---- layer-1 A-frag for this wave's ch tile (W1 hi/lo + b1 folded) ----
    // lh0 slots: (w0h,w0l),(w0h,w1h),(w1l,w1h),(w2h,w2l)  <-> B: (f0h,f0h),(f0l,f1h),(f1h,f1l),(f2h,f2h)
    // lh1 slots: (w2h,b1h),(b1l,0),0,0                    <-> B: (f2l,1.0),(1.0,0),0,0
    short8 w1f;
    {
        const int ch = ct * 32 + l31;
        const float w0 = W1[ch], w1v = W1[128 + ch], w2v = W1[256 + ch], b1v = b1[ch];
        const float w0h = __uint_as_float(cvt_pk(w0, w0) << 16);
        const float w1h = __uint_as_float(cvt_pk(w1v, w1v) << 16);
        const float w2h = __uint_as_float(cvt_pk(w2v, w2v) << 16);
        const float b1h = __uint_as_float(cvt_pk(b1v, b1v) << 16);
        const float w0l = w0 - w0h, w1l = w1v - w1h, w2l = w2v - w2h, b1l = b1v - b1h;
        unsigned d[4];
        if (lh == 0) {
            d[0] = cvt_pk(w0h, w0l);
            d[1] = cvt_pk(w0h, w1h);
            d[2] = cvt_pk(w1l, w1h);
            d[3] = cvt_pk(w2h, w2l);
        } else {
            d[0] = cvt_pk(w2h, b1h);
            d[1] = cvt_pk(b1l, 0.0f);
            d[2] = 0; d[3] = 0;
        }
        __builtin_memcpy(&w1f, d, 16);
    }

    // ---- W2^T A-frags for this wave's 32 out-chs (32 VGPRs) ----
    short8 a2f[8];
    {
        const int e = ct * 32 + l31;
        #pragma unroll
        for (int ks = 0; ks < 8; ++ks) {
            const int c = 2 * ks + lh;
            unsigned t0[4];
            #pragma unroll
            for (int t = 0; t < 4; ++t) {
                const int d0 = kmap(c, 2 * t), d1 = d0 + 1;
                t0[t] = cvt_pk(W2[d0 * 128 + e], W2[d1 * 128 + e]);
            }
            __builtin_memcpy(&a2f[ks], t0, 16);
        }
    }

    // ---- W3 A-frags: 2 frags cover this wave's 32 chs (8 VGPRs) ----
    short8 w3a[2];
    #pragma unroll
    for (int m2 = 0; m2 < 2; ++m2) {
        unsigned tt[4];
        #pragma unroll
        for (int t = 0; t < 4; ++t) {
            const int chl = ((2 * t) & 3) + 8 * ((2 * t) >> 2) + 4 * lh + 16 * m2;
            const int ch0 = ct * 32 + chl, ch1 = ch0 + 1;
            const float lo = (l31 < 4) ? W3[ch0 * 4 + l31] : 0.0f;
            const float hi = (l31 < 4) ? W3[ch1 * 4 + l31] : 0.0f;
            tt[t] = cvt_pk(lo, hi);
        }
        __builtin_memcpy(&w3a[m2], tt, 16);
    }
    const float b3r = b3[w & 3];   // phase R: waves 0..3, o = w

    // block-constant: one j-row (b, i fixed)
    const int posblock = blockIdx.x * POS_PER_BLOCK;
    const int bb = posblock >> 18;
    const int i  = (posblock >> 9) & 511;
    const float q0 = gq[i * 3 + 0], q1 = gq[i * 3 + 1], q2 = gq[i * 3 + 2];
    const float* kvrow = gkv + (size_t)(bb << 9) * 3;

    // ---- feature precompute: whole j-row, once per block (1 pos/thread) ----
    // Bit-identical to the per-tile computation it replaced (R4).
    for (int jj = tid; jj < 512; jj += THREADS) {
        const float k0 = kvrow[jj * 3 + 0], k1 = kvrow[jj * 3 + 1], k2 = kvrow[jj * 3 + 2];
        const float c0 = q0 - k0, c1 = q1 - k1, c2 = q2 - k2;
        const float f0 = copysignf(__logf(1.0f + fabsf(c0)), c0);
        const float f1 = copysignf(__logf(1.0f + fabsf(c1)), c1);
        const float f2 = copysignf(__logf(1.0f + fabsf(c2)), c2);
        const unsigned u0 = cvt_pk(f0, f0), u2 = cvt_pk(f2, f2);
        const float f0h = __uint_as_float(u0 << 16);
        const float f1h = __uint_as_float(cvt_pk(f1, f1) << 16);
        const float f2h = __uint_as_float(u2 << 16);
        const float f0l = f0 - f0h, f1l = f1 - f1h, f2l = f2 - f2h;
        fA[jj][0] = u0;                    // (f0h, f0h)
        fA[jj][1] = cvt_pk(f0l, f1);       // (f0l, f1h)
        fA[jj][2] = cvt_pk(f1, f1l);       // (f1h, f1l)
        fA[jj][3] = u2;                    // (f2h, f2h)
        fB[jj]    = cvt_pk(f2l, 1.0f);     // (f2l, 1.0) ; word1 is const
    }
    __syncthreads();   // features + b2s visible to all waves

    // ======== phase A: B-frag from LDS -> layer-1 MFMA -> ash[buf] ========
    auto phaseA = [&](int x, int buf) {
        const int jpos = x * TILE + pofs;
        unsigned d[4];
        if (lh == 0) {
            const uint4v t = *(const uint4v*)&fA[jpos][0];
            d[0] = t[0]; d[1] = t[1]; d[2] = t[2]; d[3] = t[3];
        } else {
            d[0] = fB[jpos];
            d[1] = 0x00003F80u;            // (bf16 1.0, 0) <- picks up b1
            d[2] = 0; d[3] = 0;
        }
        short8 bf; __builtin_memcpy(&bf, d, 16);

        float16 c1r = __builtin_amdgcn_mfma_f32_32x32x16_bf16(w1f, bf, z16, 0, 0, 0);
        unsigned pk0[4], pk1[4];
        #pragma unroll
        for (int t = 0; t < 4; ++t) {
            pk0[t] = cvt_pk(fmaxf(c1r[2 * t], 0.f),     fmaxf(c1r[2 * t + 1], 0.f));
            pk1[t] = cvt_pk(fmaxf(c1r[8 + 2 * t], 0.f), fmaxf(c1r[8 + 2 * t + 1], 0.f));
        }
        short8 v0, v1;
        __builtin_memcpy(&v0, pk0, 16);
        __builtin_memcpy(&v1, pk1, 16);
        *(short8*)&ash[buf][(4 * ct + lh) * CH + pofs * 8]     = v0;   // m=0 octet
        *(short8*)&ash[buf][(4 * ct + 2 + lh) * CH + pofs * 8] = v1;   // m=1 octet
    };

    phaseA(0, 0);
    __syncthreads();   // fences ash[0]

    for (int it = 0; it < ITERS; ++it) {
        const int buf = it & 1;
        const int jb = it * TILE;

        // ======== phase B: layer-2; 8 B-reads feed 8 MFMAs (1 ch tile) ========
        float16 acc;
        #pragma unroll
        for (int qr = 0; qr < 4; ++qr) {
            float4v i0 = *(const float4v*)&b2s[ct * 32 + 8 * qr + 4 * lh];
            #pragma unroll
            for (int t = 0; t < 4; ++t) acc[4 * qr + t] = i0[t];
        }
        const unsigned short* br = &ash[buf][lh * CH + pofs * 8];

        // T5: boost issue priority through the dense MFMA region (R3: -2.7%).
        __builtin_amdgcn_s_setprio(1);
        #pragma unroll
        for (int ks = 0; ks < 8; ++ks) {
            short8 bfrag = *(const short8*)(br + ks * 2 * CH);
            acc = __builtin_amdgcn_mfma_f32_32x32x16_bf16(a2f[ks], bfrag, acc, 0, 0, 0);
        }

        // ======== phase C': in-register relu + layer-3 (2 MFMAs, partial over 32 chs) ========
        {
            unsigned pa0[4], pa1[4];
            #pragma unroll
            for (int t = 0; t < 4; ++t) {
                pa0[t] = cvt_pk(fmaxf(acc[2 * t], 0.f),     fmaxf(acc[2 * t + 1], 0.f));
                pa1[t] = cvt_pk(fmaxf(acc[8 + 2 * t], 0.f), fmaxf(acc[8 + 2 * t + 1], 0.f));
            }
            short8 fa0, fa1;
            __builtin_memcpy(&fa0, pa0, 16); __builtin_memcpy(&fa1, pa1, 16);
            float16 p;
            p = __builtin_amdgcn_mfma_f32_32x32x16_bf16(w3a[0], fa0, z16, 0, 0, 0);
            p = __builtin_amdgcn_mfma_f32_32x32x16_bf16(w3a[1], fa1, p, 0, 0, 0);
            __builtin_amdgcn_s_setprio(0);
            if (lh == 0) {
                #pragma unroll
                for (int o = 0; o < 4; ++o)
                    red[buf][ct * 256 + o * 64 + pofs] = p[o];
            }
        }

        // ======== phase A for next tile (other ash buffer) ========
        if (it != ITERS - 1) phaseA(it + 1, 1 - buf);

        __syncthreads();   // single barrier/tile: fences ash[1-buf] and red[buf]

        // ======== phase R: sum 4 ct-partials + b3, coalesced store (waves 0..3) ========
        if (w < 4) {
            const int o = w, pos = lane;
            const float v = b3r
                          + red[buf][0 * 256 + o * 64 + pos]
                          + red[buf][1 * 256 + o * 64 + pos]
                          + red[buf][2 * 256 + o * 64 + pos]
                          + red[buf][3 * 256 + o * 64 + pos];
            out[((size_t)((bb << 2) + o) << 18) + ((size_t)i << 9) + jb + pos] = v;
        }
    }
}

extern "C" void kernel_launch(void* const* d_in, const int* in_sizes, int n_in,
                              void* d_out, int out_size, void* d_ws, size_t ws_size,
                              hipStream_t stream) {
    const float* gq  = (const float*)d_in[0];
    const float* gkv = (const float*)d_in[1];
    const float* W1  = (const float*)d_in[2];
    const float* b1  = (const float*)d_in[3];
    const float* W2  = (const float*)d_in[4];
    const float* b2  = (const float*)d_in[5];
    const float* W3  = (const float*)d_in[6];
    const float* b3  = (const float*)d_in[7];
    float* out = (float*)d_out;

    crpb_mfma8<<<NBLOCKS, THREADS, 0, stream>>>(gq, gkv, W1, b1, W2, b2, W3, b3, out);
}